// Round 10
// baseline (135.045 us; speedup 1.0000x reference)
//
#include <hip/hip_runtime.h>
#include <math.h>

// BERT-CRF forward NLL on MI355X — register-only serial recursion, one item
// per 64-lane wave.
//
// Round-8 (resubmitted unchanged after infra failure). r7 (4 indep chains)
// was NEUTRAL vs r5 => the ~85cyc/step excess over the ~6cyc/instr cadence
// line is not chain latency. Marginal cost of r7's +3 plain adds was ~2cyc
// each, while the 16 adjacent DPP ops in the asm block average ~9+cyc =>
// hypothesis: DPP-dense blocks with no interleaved non-DPP work issue at a
// penalty; compiler can't fill slots inside an asm block. This version:
//  - ONE asm block per step: matvec (16 fused DPP mul/fmac, 4 chains)
//    + v_exp_f32 woven between DPPs (the only independent long-latency op)
//    + tree adds + permlane-swap combine + final xF mul, all inside.
//  - Emission arg unified: fe = fmaf(feat, LOG2E, -kfF), kfF=0 on
//    non-renorm steps (compiler folds to mul), so one asm shape; two
//    variants only for permlane16 (alpha) vs permlane32 (beta).
// Layouts/tables/renorm/prefetch/gold identical to PASSING r7:
//   L1 rows hold tag blocks A,B,A,B ; L2 rows A,A,B,B
//   alpha (L1->L2): permlane16_swap ; beta (L2->L1): permlane32_swap,
//   combine = r0+r1 of equal-input swap.

constexpr int NTAG = 32;
constexpr int TSTART = 30;
constexpr int TSTOP = 31;
constexpr int NB = 1024;
constexpr int NS = 512;

constexpr float LOG2E = 1.44269504088896340736f;
constexpr float LN2   = 0.69314718055994530942f;

__device__ __forceinline__ float fexp2(float x) {
#if __has_builtin(__builtin_amdgcn_exp2f)
    return __builtin_amdgcn_exp2f(x);
#else
    return exp2f(x);
#endif
}

// Full CRF step in one asm block.
//  %0=xn  %1..%4=acc chains  %5=F temp  %6=x  %7=fe(exp2 arg)  %8..%23=T[0..15]
// Entry s_nop guards prev-step x-write -> DPP-read. v_exp placed after the
// 4 chain-opening muls (fills DPP slots; latency covered before final mul).
// Combine: mov+swap+add with s_nops for VALU->permlane hazards.
#define STEP_ASM(XN, T0_, T1_, T2_, T3_, TF_, XV, FE, T, SWAPOP)              \
    asm("s_nop 1\n\t"                                                         \
        "v_mul_f32 %1, %6, %8\n\t"                                            \
        "v_mul_f32 %2, %6, %9 row_ror:1 row_mask:0xf bank_mask:0xf\n\t"       \
        "v_mul_f32 %3, %6, %10 row_ror:2 row_mask:0xf bank_mask:0xf\n\t"      \
        "v_mul_f32 %4, %6, %11 row_ror:3 row_mask:0xf bank_mask:0xf\n\t"      \
        "v_exp_f32 %5, %7\n\t"                                                \
        "v_fmac_f32 %1, %6, %12 row_ror:4 row_mask:0xf bank_mask:0xf\n\t"     \
        "v_fmac_f32 %2, %6, %13 row_ror:5 row_mask:0xf bank_mask:0xf\n\t"     \
        "v_fmac_f32 %3, %6, %14 row_ror:6 row_mask:0xf bank_mask:0xf\n\t"     \
        "v_fmac_f32 %4, %6, %15 row_ror:7 row_mask:0xf bank_mask:0xf\n\t"     \
        "v_fmac_f32 %1, %6, %16 row_ror:8 row_mask:0xf bank_mask:0xf\n\t"     \
        "v_fmac_f32 %2, %6, %17 row_ror:9 row_mask:0xf bank_mask:0xf\n\t"     \
        "v_fmac_f32 %3, %6, %18 row_ror:10 row_mask:0xf bank_mask:0xf\n\t"    \
        "v_fmac_f32 %4, %6, %19 row_ror:11 row_mask:0xf bank_mask:0xf\n\t"    \
        "v_fmac_f32 %1, %6, %20 row_ror:12 row_mask:0xf bank_mask:0xf\n\t"    \
        "v_fmac_f32 %2, %6, %21 row_ror:13 row_mask:0xf bank_mask:0xf\n\t"    \
        "v_fmac_f32 %3, %6, %22 row_ror:14 row_mask:0xf bank_mask:0xf\n\t"    \
        "v_fmac_f32 %4, %6, %23 row_ror:15 row_mask:0xf bank_mask:0xf\n\t"    \
        "v_add_f32 %1, %1, %2\n\t"                                            \
        "v_add_f32 %3, %3, %4\n\t"                                            \
        "v_add_f32 %1, %1, %3\n\t"                                            \
        "v_mov_b32 %2, %1\n\t"                                                \
        "s_nop 1\n\t"                                                         \
        SWAPOP " %2, %1\n\t"                                                  \
        "s_nop 1\n\t"                                                         \
        "v_add_f32 %1, %2, %1\n\t"                                            \
        "v_mul_f32 %0, %1, %5"                                                \
        : "=&v"(XN), "=&v"(T0_), "=&v"(T1_), "=&v"(T2_), "=&v"(T3_),          \
          "=&v"(TF_)                                                          \
        : "v"(XV), "v"(FE), "v"(T[0]), "v"(T[1]), "v"(T[2]), "v"(T[3]),       \
          "v"(T[4]), "v"(T[5]), "v"(T[6]), "v"(T[7]), "v"(T[8]), "v"(T[9]),   \
          "v"(T[10]), "v"(T[11]), "v"(T[12]), "v"(T[13]), "v"(T[14]),         \
          "v"(T[15]))

__global__ __launch_bounds__(64)
void crf_fwd(const float* __restrict__ feats,
             const int*   __restrict__ labels,
             const int*   __restrict__ lengths,
             const float* __restrict__ trans,
             float*       __restrict__ out)
{
    const int j   = threadIdx.x;   // 0..63
    const int j32 = j & 31;
    const int b   = blockIdx.x;

    const int i  = j & 15;          // position within 16-lane row
    const int c1 = j & 16;          // row-parity bit (rows 1,3)
    const int c2 = (j & 32) >> 1;   // half bit as tag-block bit (rows 2,3)

    // Scalar coefficient tables, indexed by rotation amount N:
    //   alpha (L1->L2): src = ((i-N)&15)|c1 , dst-col = i|c2   -> TmS
    //   beta  (L2->L1): src = ((i-N)&15)|c2 , dst-col = i|c1   -> TsS
    float TmS[16], TsS[16];
    #pragma unroll
    for (int N = 0; N < 16; ++N) {
        int s15 = (i - N) & 15;
        TmS[N] = fexp2(trans[((s15 | c1) << 5) + (i | c2)] * LOG2E);
        TsS[N] = fexp2(trans[((s15 | c2) << 5) + (i | c1)] * LOG2E);
    }

    const int len = lengths[b];
    const float* fb = feats  + (size_t)b * NS * NTAG;
    const int*   lb = labels + (size_t)b * NS;

    // labels for this item, staged into registers (coalesced, off the loop)
    int labr[8];
    #pragma unroll
    for (int k = 0; k < 8; ++k)
        labr[k] = lb[(k << 6) + j];

    // Emission-factor / prefetch index per step parity:
    //   after alpha (odd t): layout L2, tag = i|c2
    //   after beta  (even t): layout L1, tag = j32
    const int fxA = i | c2;
    const int fxB = j32;

    // t = 0 : layout L1, lane j holds P0[j32]
    float x = fexp2((fb[j32] + trans[(TSTART << 5) + j32]) * LOG2E);

    int bits0 = __builtin_amdgcn_readfirstlane(__float_as_int(x));
    int e0    = min(max((bits0 >> 23) & 0xFF, 1), 254);
    int kreg  = e0 - 127;
    int creg  = 0;

    // feats prefetch pipeline (8 deep); slot u serves steps t with t%2==(1+u)%2
    float pf[8];
    #pragma unroll
    for (int u = 0; u < 8; ++u) {
        int tt = min(1 + u, NS - 1);
        pf[u] = fb[(size_t)tt * NTAG + ((u & 1) ? fxB : fxA)];
    }

    const int nsteps = len - 1;        // recursion steps t = 1..len-1
    const int nchunk = nsteps >> 3;
    const int rem    = nsteps & 7;
    int t = 1;

    // TBL: TmS (alpha, permlane16) or TsS (beta, permlane32);
    // RN = 1: fold 2^-kreg into emission factor and re-extract kreg.
    #define CRF_STEP(FEAT, TBL, SWANAME, RN)                                  \
    {                                                                         \
        float kfF = 0.0f;                                                     \
        if (RN) {                                                             \
            creg += kreg;                                                     \
            kfF = (float)kreg;                                                \
        }                                                                     \
        float fe = fmaf((FEAT), LOG2E, -kfF);                                 \
        float xn_, q0_, q1_, q2_, q3_, qf_;                                   \
        STEP_ASM(xn_, q0_, q1_, q2_, q3_, qf_, x, fe, TBL, SWANAME);          \
        x = xn_;                                                              \
        if (RN) {                                                             \
            int bits_ = __builtin_amdgcn_readfirstlane(__float_as_int(x));    \
            int e_ = min(max((bits_ >> 23) & 0xFF, 1), 254);                  \
            kreg = e_ - 127;                                                  \
        }                                                                     \
    }

    for (int ci = 0; ci < nchunk; ++ci) {
        #pragma unroll
        for (int u = 0; u < 8; ++u) {
            float feat = pf[u];
            int   tp   = min(t + 8, NS - 1);
            pf[u] = fb[(size_t)tp * NTAG + ((u & 1) ? fxB : fxA)];
            if (u & 1) { CRF_STEP(feat, TsS, "v_permlane32_swap_b32", 1) }
            else       { CRF_STEP(feat, TmS, "v_permlane16_swap_b32", 0) }
            ++t;
        }
    }
    // remainder (<8 steps); pf[u] holds feats for t = 1+8*nchunk+u
    #pragma unroll
    for (int u = 0; u < 7; ++u) {
        if (u < rem) {
            if (u & 1) { CRF_STEP(pf[u], TsS, "v_permlane32_swap_b32", 1) }
            else       { CRF_STEP(pf[u], TmS, "v_permlane16_swap_b32", 0) }
            ++t;
        }
    }
    #undef CRF_STEP

    // Every tag appears exactly twice across the 64 lanes in BOTH layouts,
    // so the full 64-lane butterfly gives 2*sum(P); subtract ln2.
    float s = x;
    #pragma unroll
    for (int m = 1; m <= 32; m <<= 1)
        s += __shfl_xor(s, m, 64);
    float fwd = (float)creg * LN2 + logf(s) - LN2;

    // ---- gold score: parallel gather tail (latency-tolerant) ----
    float gold = 0.0f;
    #pragma unroll
    for (int k = 0; k < 8; ++k) {
        int tt = (k << 6) + j;
        if (tt < len) {
            int lab_t = labr[k];
            gold += fb[(size_t)tt * NTAG + lab_t];               // emit
            if (tt > 0)
                gold += trans[(lb[tt - 1] << 5) + lab_t];        // pair
            else
                gold += trans[(TSTART << 5) + lab_t];            // start
            if (tt == len - 1)
                gold += trans[(lab_t << 5) + TSTOP];             // stop
        }
    }
    // reduce gold over all 64 lanes (each (b,t) counted once)
    #pragma unroll
    for (int m = 1; m <= 32; m <<= 1)
        gold += __shfl_xor(gold, m, 64);

    if (j == 0)
        atomicAdd(out, (fwd - gold) * (1.0f / 1024.0f));
}

extern "C" void kernel_launch(void* const* d_in, const int* in_sizes, int n_in,
                              void* d_out, int out_size, void* d_ws, size_t ws_size,
                              hipStream_t stream) {
    const float* feats   = (const float*)d_in[0];
    const int*   labels  = (const int*)d_in[1];
    const int*   lengths = (const int*)d_in[2];
    const float* trans   = (const float*)d_in[3];
    float*       out     = (float*)d_out;

    hipMemsetAsync(out, 0, sizeof(float) * (size_t)out_size, stream);
    crf_fwd<<<dim3(NB), dim3(64), 0, stream>>>(feats, labels, lengths, trans, out);
}

// Round 11
// 132.742 us; speedup vs baseline: 1.0173x; 1.0173x over previous
//
#include <hip/hip_runtime.h>
#include <math.h>

// BERT-CRF forward NLL on MI355X — register-only serial recursion, one item
// per 64-lane wave.
//
// Round-10. Model refit over r0-r8: T_step ≈ 9·N_DPP + 4.4·N_plain + 40 cyc
// (solo wave/SIMD; DPP-class ops ~2x plain issue cost). r7 (4 chains) vs r5
// (1 chain) proved accumulator-chain latency is irrelevant => use the
// minimum-slot single-chain matvec (16 instrs, 15 DPP). Remaining cuts:
//  - renorm every 4TH step (u==3,7). Bound: worst-tail growth 2^20/step x 4
//    + 2^12 cross-lane spread ≈ 2^92 << 2^127. Saves ~0.5 slot/step.
//  - combine tail (mov/swap/add/mul) inside the asm block with exactly two
//    hazard s_nops (VALU->permlane-read, permlane-write->VALU-read).
// Floor arithmetic: 15 mandatory DPP gathers (1 per product, 16 products
// per lane = perfect 64-lane split of the 1024-product matvec) + ~10 glue
// => ~210-230 cyc/step. At 511 steps => ~45-49 µs dispatch.
// Layouts/tables/prefetch/gold identical to PASSING r4-r8:
//   L1 rows hold tag blocks A,B,A,B ; L2 rows A,A,B,B
//   alpha (L1->L2): permlane16_swap ; beta (L2->L1): permlane32_swap,
//   combine = r0+r1 of equal-input swap.

constexpr int NTAG = 32;
constexpr int TSTART = 30;
constexpr int TSTOP = 31;
constexpr int NB = 1024;
constexpr int NS = 512;

constexpr float LOG2E = 1.44269504088896340736f;
constexpr float LN2   = 0.69314718055994530942f;

__device__ __forceinline__ float fexp2(float x) {
#if __has_builtin(__builtin_amdgcn_exp2f)
    return __builtin_amdgcn_exp2f(x);
#else
    return exp2f(x);
#endif
}

// Full step core: 16-term gathered dot (single fmac chain, DPP row_ror fused)
// + equal-input permlane combine + emission scale, one asm block.
//  %0=acc  %1=tmp  %2=x  %3=F  %4..%19=T[0..15]
// Hazards: x's DPP-read is >=3 instrs after its write (prev block's mul +
// glue + this block's opening mul) — no entry nop needed, but the mov->swap
// (VALU write -> permlane cross-lane read) and swap->add (permlane write ->
// VALU read) windows each get s_nop 1.
#define STEP_ASM(ACC, TMP, XV, FV, T, SWAPOP)                                 \
    asm("v_mul_f32 %0, %2, %4\n\t"                                            \
        "v_fmac_f32 %0, %2, %5 row_ror:1 row_mask:0xf bank_mask:0xf\n\t"      \
        "v_fmac_f32 %0, %2, %6 row_ror:2 row_mask:0xf bank_mask:0xf\n\t"      \
        "v_fmac_f32 %0, %2, %7 row_ror:3 row_mask:0xf bank_mask:0xf\n\t"      \
        "v_fmac_f32 %0, %2, %8 row_ror:4 row_mask:0xf bank_mask:0xf\n\t"      \
        "v_fmac_f32 %0, %2, %9 row_ror:5 row_mask:0xf bank_mask:0xf\n\t"      \
        "v_fmac_f32 %0, %2, %10 row_ror:6 row_mask:0xf bank_mask:0xf\n\t"     \
        "v_fmac_f32 %0, %2, %11 row_ror:7 row_mask:0xf bank_mask:0xf\n\t"     \
        "v_fmac_f32 %0, %2, %12 row_ror:8 row_mask:0xf bank_mask:0xf\n\t"     \
        "v_fmac_f32 %0, %2, %13 row_ror:9 row_mask:0xf bank_mask:0xf\n\t"     \
        "v_fmac_f32 %0, %2, %14 row_ror:10 row_mask:0xf bank_mask:0xf\n\t"    \
        "v_fmac_f32 %0, %2, %15 row_ror:11 row_mask:0xf bank_mask:0xf\n\t"    \
        "v_fmac_f32 %0, %2, %16 row_ror:12 row_mask:0xf bank_mask:0xf\n\t"    \
        "v_fmac_f32 %0, %2, %17 row_ror:13 row_mask:0xf bank_mask:0xf\n\t"    \
        "v_fmac_f32 %0, %2, %18 row_ror:14 row_mask:0xf bank_mask:0xf\n\t"    \
        "v_fmac_f32 %0, %2, %19 row_ror:15 row_mask:0xf bank_mask:0xf\n\t"    \
        "v_mov_b32 %1, %0\n\t"                                                \
        "s_nop 1\n\t"                                                         \
        SWAPOP " %0, %1\n\t"                                                  \
        "s_nop 1\n\t"                                                         \
        "v_add_f32 %0, %0, %1\n\t"                                            \
        "v_mul_f32 %0, %0, %3"                                                \
        : "=&v"(ACC), "=&v"(TMP)                                              \
        : "v"(XV), "v"(FV), "v"(T[0]), "v"(T[1]), "v"(T[2]), "v"(T[3]),       \
          "v"(T[4]), "v"(T[5]), "v"(T[6]), "v"(T[7]), "v"(T[8]), "v"(T[9]),   \
          "v"(T[10]), "v"(T[11]), "v"(T[12]), "v"(T[13]), "v"(T[14]),         \
          "v"(T[15]))

__global__ __launch_bounds__(64)
void crf_fwd(const float* __restrict__ feats,
             const int*   __restrict__ labels,
             const int*   __restrict__ lengths,
             const float* __restrict__ trans,
             float*       __restrict__ out)
{
    const int j   = threadIdx.x;   // 0..63
    const int j32 = j & 31;
    const int b   = blockIdx.x;

    const int i  = j & 15;          // position within 16-lane row
    const int c1 = j & 16;          // row-parity bit (rows 1,3)
    const int c2 = (j & 32) >> 1;   // half bit as tag-block bit (rows 2,3)

    // Scalar coefficient tables, indexed by rotation amount N:
    //   alpha (L1->L2): src = ((i-N)&15)|c1 , dst-col = i|c2   -> TmS
    //   beta  (L2->L1): src = ((i-N)&15)|c2 , dst-col = i|c1   -> TsS
    float TmS[16], TsS[16];
    #pragma unroll
    for (int N = 0; N < 16; ++N) {
        int s15 = (i - N) & 15;
        TmS[N] = fexp2(trans[((s15 | c1) << 5) + (i | c2)] * LOG2E);
        TsS[N] = fexp2(trans[((s15 | c2) << 5) + (i | c1)] * LOG2E);
    }

    const int len = lengths[b];
    const float* fb = feats  + (size_t)b * NS * NTAG;
    const int*   lb = labels + (size_t)b * NS;

    // labels for this item, staged into registers (coalesced, off the loop)
    int labr[8];
    #pragma unroll
    for (int k = 0; k < 8; ++k)
        labr[k] = lb[(k << 6) + j];

    // Emission-factor / prefetch index per step parity:
    //   after alpha (odd t): layout L2, tag = i|c2
    //   after beta  (even t): layout L1, tag = j32
    const int fxA = i | c2;
    const int fxB = j32;

    // t = 0 : layout L1, lane j holds P0[j32]
    float x = fexp2((fb[j32] + trans[(TSTART << 5) + j32]) * LOG2E);

    int bits0 = __builtin_amdgcn_readfirstlane(__float_as_int(x));
    int e0    = min(max((bits0 >> 23) & 0xFF, 1), 254);
    int kreg  = e0 - 127;
    int creg  = 0;

    // feats prefetch pipeline (8 deep); slot u serves steps t with t%2==(1+u)%2
    float pf[8];
    #pragma unroll
    for (int u = 0; u < 8; ++u) {
        int tt = min(1 + u, NS - 1);
        pf[u] = fb[(size_t)tt * NTAG + ((u & 1) ? fxB : fxA)];
    }

    const int nsteps = len - 1;        // recursion steps t = 1..len-1
    const int nchunk = nsteps >> 3;
    const int rem    = nsteps & 7;
    int t = 1;

    // TBL: TmS (alpha, permlane16) or TsS (beta, permlane32);
    // RN = 1: fold 2^-kreg into emission factor and re-extract kreg.
    #define CRF_STEP(FEAT, TBL, SWANAME, RN)                                  \
    {                                                                         \
        float F_;                                                             \
        if (RN) {                                                             \
            creg += kreg;                                                     \
            F_ = fexp2(fmaf((FEAT), LOG2E, -(float)kreg));                    \
        } else {                                                              \
            F_ = fexp2((FEAT) * LOG2E);                                       \
        }                                                                     \
        float acc_, tmp_;                                                     \
        STEP_ASM(acc_, tmp_, x, F_, TBL, SWANAME);                            \
        x = acc_;                                                             \
        if (RN) {                                                             \
            int bits_ = __builtin_amdgcn_readfirstlane(__float_as_int(x));    \
            int e_ = min(max((bits_ >> 23) & 0xFF, 1), 254);                  \
            kreg = e_ - 127;                                                  \
        }                                                                     \
    }

    for (int ci = 0; ci < nchunk; ++ci) {
        #pragma unroll
        for (int u = 0; u < 8; ++u) {
            float feat = pf[u];
            int   tp   = min(t + 8, NS - 1);
            pf[u] = fb[(size_t)tp * NTAG + ((u & 1) ? fxB : fxA)];
            if (u == 3 || u == 7) {                     // renorm every 4th
                CRF_STEP(feat, TsS, "v_permlane32_swap_b32", 1)
            } else if (u & 1) {
                CRF_STEP(feat, TsS, "v_permlane32_swap_b32", 0)
            } else {
                CRF_STEP(feat, TmS, "v_permlane16_swap_b32", 0)
            }
            ++t;
        }
    }
    // remainder (<8 steps); pf[u] holds feats for t = 1+8*nchunk+u
    #pragma unroll
    for (int u = 0; u < 7; ++u) {
        if (u < rem) {
            if (u == 3) {
                CRF_STEP(pf[u], TsS, "v_permlane32_swap_b32", 1)
            } else if (u & 1) {
                CRF_STEP(pf[u], TsS, "v_permlane32_swap_b32", 0)
            } else {
                CRF_STEP(pf[u], TmS, "v_permlane16_swap_b32", 0)
            }
            ++t;
        }
    }
    #undef CRF_STEP

    // Every tag appears exactly twice across the 64 lanes in BOTH layouts,
    // so the full 64-lane butterfly gives 2*sum(P); subtract ln2.
    float s = x;
    #pragma unroll
    for (int m = 1; m <= 32; m <<= 1)
        s += __shfl_xor(s, m, 64);
    float fwd = (float)creg * LN2 + logf(s) - LN2;

    // ---- gold score: parallel gather tail (latency-tolerant) ----
    float gold = 0.0f;
    #pragma unroll
    for (int k = 0; k < 8; ++k) {
        int tt = (k << 6) + j;
        if (tt < len) {
            int lab_t = labr[k];
            gold += fb[(size_t)tt * NTAG + lab_t];               // emit
            if (tt > 0)
                gold += trans[(lb[tt - 1] << 5) + lab_t];        // pair
            else
                gold += trans[(TSTART << 5) + lab_t];            // start
            if (tt == len - 1)
                gold += trans[(lab_t << 5) + TSTOP];             // stop
        }
    }
    // reduce gold over all 64 lanes (each (b,t) counted once)
    #pragma unroll
    for (int m = 1; m <= 32; m <<= 1)
        gold += __shfl_xor(gold, m, 64);

    if (j == 0)
        atomicAdd(out, (fwd - gold) * (1.0f / 1024.0f));
}

extern "C" void kernel_launch(void* const* d_in, const int* in_sizes, int n_in,
                              void* d_out, int out_size, void* d_ws, size_t ws_size,
                              hipStream_t stream) {
    const float* feats   = (const float*)d_in[0];
    const int*   labels  = (const int*)d_in[1];
    const int*   lengths = (const int*)d_in[2];
    const float* trans   = (const float*)d_in[3];
    float*       out     = (float*)d_out;

    hipMemsetAsync(out, 0, sizeof(float) * (size_t)out_size, stream);
    crf_fwd<<<dim3(NB), dim3(64), 0, stream>>>(feats, labels, lengths, trans, out);
}